// Round 9
// baseline (196.961 us; speedup 1.0000x reference)
//
#include <hip/hip_runtime.h>
#include <hip/hip_bf16.h>

#define DEVINL __device__ __forceinline__

typedef __attribute__((ext_vector_type(8)))  short short8;
typedef __attribute__((ext_vector_type(4)))  float float4v;

DEVINL float bf2f(unsigned short u) { return __uint_as_float(((unsigned)u) << 16); }
DEVINL unsigned short f2bf(float f) {            // round-to-nearest-even
  unsigned u = __float_as_uint(f);
  unsigned r = u + 0x7FFFu + ((u >> 16) & 1u);
  return (unsigned short)(r >> 16);
}

// region: 0=center,1=TL,2=top,3=TR,4=right,5=BR,6=bottom,7=BL,8=left
DEVINL int region_of(int h, int w, int n) {
  if (h == 0)     return (w == 0) ? 1 : ((w == n-1) ? 3 : 2);
  if (h == n-1)   return (w == 0) ? 7 : ((w == n-1) ? 5 : 6);
  return (w == 0) ? 8 : ((w == n-1) ? 4 : 0);
}

// ---- sentinel: encodes an environment-assumption failure into d_out ----
__global__ void sentinel_k(float* out, float v) {
  int t = blockIdx.x*64 + threadIdx.x;
  if (t < 320) out[t] = v;
}

// ---- weight transpose into MFMA B-fragment layout, fp32 -> bf16 (3 tensors) ----
// B-frag (16x16x32): lane holds B[k = (lane>>4)*8 + j][n = lane&15], j=0..7.
__global__ void wtrans_all(const float* __restrict__ W2, const float* __restrict__ W3,
                           const float* __restrict__ W4,
                           unsigned short* __restrict__ T2, unsigned short* __restrict__ T3,
                           unsigned short* __restrict__ T4)
{
  int y = blockIdx.y;
  const float* W = (y == 0) ? W2 : (y == 1) ? W3 : W4;
  unsigned short* T = (y == 0) ? T2 : (y == 1) ? T3 : T4;
  int Ksteps = (y == 2) ? 36 : 18;
  int NT = (y == 0) ? 4 : 8;
  int F  = (y == 0) ? 64 : 128;
  int i = blockIdx.x*256 + threadIdx.x;
  if (i >= Ksteps*NT*64) return;
  int lane = i & 63, nt = (i >> 6) % NT, kstep = i / (64*NT);
  int f = nt*16 + (lane & 15);
  int kbase = kstep*32 + (lane >> 4)*8;
  unsigned short v[8];
  #pragma unroll
  for (int j = 0; j < 8; j++) v[j] = f2bf(W[(kbase + j)*F + f]);
  ushort4* q = (ushort4*)&T[(size_t)i * 8];
  q[0] = make_ushort4(v[0], v[1], v[2], v[3]);
  q[1] = make_ushort4(v[4], v[5], v[6], v[7]);
}

// ---- conv1: C=1 -> F=64, N=64, u-domain; fp32 x in, bf16 u1 out (vector ALU) ----
__global__ __launch_bounds__(256) void conv1_k(const float* __restrict__ x,
    const float* __restrict__ Wf, const float* __restrict__ Df,
    unsigned short* __restrict__ out)
{
  int h = blockIdx.x, b = blockIdx.y, t = threadIdx.x;
  __shared__ float a[3][66];
  for (int idx = t; idx < 3*66; idx += 256) {
    int dy = idx / 66, wcol = idx % 66;
    int hh = h + dy - 1, w = wcol - 1;
    float v = 0.f;
    if (hh >= 0 && hh < 64 && w >= 0 && w < 64)
      v = x[(b*64 + hh)*64 + w];
    a[dy][wcol] = v;
  }
  __syncthreads();
  int f = t & 63, wq = t >> 6;
  float wk[9];
  #pragma unroll
  for (int k = 0; k < 9; k++) wk[k] = Wf[k*64 + f];
  for (int wi = 0; wi < 16; wi++) {
    int w = wq*16 + wi;
    float acc = 0.f;
    #pragma unroll
    for (int dy = 0; dy < 3; dy++)
      #pragma unroll
      for (int dx = 0; dx < 3; dx++)
        acc += a[dy][w+dx] * wk[dy*3+dx];
    int r = region_of(h, w, 64);
    out[((b*64 + h)*64 + w)*64 + f] = f2bf(fminf(acc - Df[r*64 + f], 0.f));
  }
}

// ---- MFMA u-domain conv (+ optional fused 2x2 pool): bf16 NHWC, fp32 accum ----
// Implicit GEMM: M = w positions, N = F, K = 9*C. mfma_f32_16x16x32_bf16.
// Wave decomposition (R8 fix): wave = (m-group, n-group); each wave reads A
// from LDS only for ITS m-tile (was: all m-tiles per wave -> 4x redundant LDS
// traffic, LDS-bound at ~6x the MFMA time). B-frags come from L2-resident Wt.
// conv2: 4 m-groups x 1 n-group; conv3/4: 2 x 2. WN = 4 n-tiles/wave always.
template<int C, int F, int N, bool POOL>
__global__ __launch_bounds__(256) void conv_mfma(
    const unsigned short* __restrict__ U, const unsigned short* __restrict__ Wt,
    const float* __restrict__ Df, unsigned short* __restrict__ out)
{
  constexpr int RC   = POOL ? 2 : 1;   // rows computed
  constexpr int ROWS = RC + 2;         // rows staged
  constexpr int Cpad = C + 8;          // mult of 8: 16B-aligned ds_read_b128;
                                       // banks 4*(lm+quad)%32: exactly 8/bank
  constexpr int NT = F / 16;
  constexpr int MT = N / 16;
  constexpr int NG = 4 / MT;           // n-groups (conv2:1, conv3/4:2)
  static_assert(NT/NG == 4, "WN must be 4");

  __shared__ __align__(16) unsigned short lds[ROWS*(N+2)*Cpad];

  int b = blockIdx.y, hp = blockIdx.x, t = threadIdx.x;
  int h0 = hp * RC;

  // stage rows h0-1 .. h0+RC (16B chunks, zero halo)
  const int stage16 = ROWS*(N+2)*(C/8);
  for (int i = t; i < stage16; i += 256) {
    int c8 = i % (C/8), wc = (i/(C/8)) % (N+2), r = i/((C/8)*(N+2));
    int hh = h0 - 1 + r, w = wc - 1;
    float4 v = make_float4(0.f,0.f,0.f,0.f);
    if (hh >= 0 && hh < N && w >= 0 && w < N)
      v = *(const float4*)&U[(((size_t)b*N + hh)*N + w)*C + c8*8];
    *(float4*)&lds[(r*(N+2) + wc)*Cpad + c8*8] = v;
  }
  __syncthreads();

  int lane = t & 63, wave = t >> 6;
  int quad = lane >> 4, lm = lane & 15;
  int mg = (NG == 1) ? wave : (wave >> 1);     // m-tile owned by this wave
  int ng = (NG == 1) ? 0    : (wave & 1);      // n-group owned by this wave

  union ABu { float4 f4; short8 v; };

  float4v acc[RC][4];
  #pragma unroll
  for (int hi = 0; hi < RC; hi++)
    #pragma unroll
    for (int n = 0; n < 4; n++)
      acc[hi][n] = (float4v){0.f, 0.f, 0.f, 0.f};

  #pragma unroll
  for (int dy = 0; dy < 3; dy++)
  #pragma unroll
  for (int dx = 0; dx < 3; dx++)
  for (int c0 = 0; c0 < C; c0 += 32) {
    int kstep = (dy*3 + dx)*(C/32) + (c0 >> 5);
    ABu bfr[4];
    #pragma unroll
    for (int n = 0; n < 4; n++)
      bfr[n].f4 = *(const float4*)&Wt[(size_t)((kstep*NT + ng*4 + n)*64 + lane)*8];
    ABu afr[RC];
    #pragma unroll
    for (int hi = 0; hi < RC; hi++)
      afr[hi].f4 = *(const float4*)&lds[((hi+dy)*(N+2) + (mg*16 + lm + dx))*Cpad + c0 + quad*8];
    #pragma unroll
    for (int hi = 0; hi < RC; hi++)
      #pragma unroll
      for (int n = 0; n < 4; n++)
        acc[hi][n] = __builtin_amdgcn_mfma_f32_16x16x32_bf16(afr[hi].v, bfr[n].v, acc[hi][n], 0, 0, 0);
  }

  // epilogue: D layout col=lane&15 (f), row=quad*4+r (w)
  if (POOL) {
    constexpr int M2 = N/2;
    #pragma unroll
    for (int n = 0; n < 4; n++) {
      int f = (ng*4 + n)*16 + lm;
      #pragma unroll
      for (int rp = 0; rp < 2; rp++) {
        float mx = -1e30f;
        #pragma unroll
        for (int hi = 0; hi < 2; hi++)
          #pragma unroll
          for (int rr = 0; rr < 2; rr++) {
            int h = h0 + hi, w = mg*16 + quad*4 + 2*rp + rr;
            float v = fminf(acc[hi][n][2*rp+rr] - Df[region_of(h, w, N)*F + f], 0.f);
            mx = fmaxf(mx, v);
          }
        int wp = mg*8 + quad*2 + rp;
        out[(((size_t)b*M2 + hp)*M2 + wp)*F + f] = f2bf(mx);
      }
    }
  } else {
    int h = h0;
    #pragma unroll
    for (int n = 0; n < 4; n++) {
      int f = (ng*4 + n)*16 + lm;
      #pragma unroll
      for (int r = 0; r < 4; r++) {
        int w = mg*16 + quad*4 + r;
        int reg = region_of(h, w, N);
        float v = fminf(acc[0][n][r] - Df[reg*F + f], 0.f);
        out[(((size_t)b*N + h)*N + w)*F + f] = f2bf(v);
      }
    }
  }
}

// ---- dense1 split-K + f-split: act bf16 [32,32768], Wd1 fp32 -> fp32 partials ----
__global__ __launch_bounds__(256) void dense_k(const unsigned short* __restrict__ act,
    const float* __restrict__ W, float* __restrict__ part)
{
  int blk = blockIdx.x, t = threadIdx.x;
  int kblk = blk >> 1, fh = blk & 1;
  int k0 = kblk * 128;
  __shared__ float a[128][36];             // [kc][b], padded
  for (int idx = t; idx < 32*128; idx += 256) {
    int bb = idx >> 7, kc = idx & 127;
    a[kc][bb] = bf2f(act[(size_t)bb*32768 + k0 + kc]);
  }
  __syncthreads();
  int f0 = fh*128 + (t & 31)*4, b0 = (t >> 5)*4;   // 4f x 4b per thread
  float acc[4][4] = {};
  for (int kc = 0; kc < 128; kc++) {
    float4 wv = *(const float4*)&W[(size_t)(k0 + kc)*256 + f0];
    #pragma unroll
    for (int bb = 0; bb < 4; bb++) {
      float av = a[kc][b0 + bb];
      acc[bb][0] += av * wv.x;
      acc[bb][1] += av * wv.y;
      acc[bb][2] += av * wv.z;
      acc[bb][3] += av * wv.w;
    }
  }
  #pragma unroll
  for (int bb = 0; bb < 4; bb++) {
    float4 v = make_float4(acc[bb][0], acc[bb][1], acc[bb][2], acc[bb][3]);
    *(float4*)&part[(size_t)kblk*8192 + (b0+bb)*256 + f0] = v;
  }
}

// ---- tail: reduce partials -> ud, then out[b,o] = Dout[o] - ud[b,:]@Wout[:,o] ----
__global__ __launch_bounds__(256) void tail_k(const float* __restrict__ part,
    const float* __restrict__ Dd, const float* __restrict__ Wo,
    const float* __restrict__ Do, float* __restrict__ out)
{
  int b = blockIdx.x, t = threadIdx.x;   // 32 blocks (one per batch), 256 thr
  __shared__ float ud[256];
  float s = 0.f;
  #pragma unroll 4
  for (int blk = 0; blk < 256; blk++) s += part[(size_t)blk*8192 + b*256 + t];
  ud[t] = fminf(s - Dd[t], 0.f);
  __syncthreads();
  if (t < 10) {
    float acc = 0.f;
    for (int f = 0; f < 256; f++) acc += ud[f] * Wo[f*10 + t];
    out[b*10 + t] = Do[t] - acc;
  }
}

extern "C" void kernel_launch(void* const* d_in, const int* in_sizes, int n_in,
                              void* d_out, int out_size, void* d_ws, size_t ws_size,
                              hipStream_t stream)
{
  float* outp = (float*)d_out;

  // --- environment asserts with sentinel outputs (validated in R4/R5) ---
  if (n_in != 13) { sentinel_k<<<5, 64, 0, stream>>>(outp, 200.f); return; }
  const int exp_sz[13] = {131072, 576, 576, 36864, 576, 73728, 1152,
                          147456, 1152, 8388608, 256, 2560, 10};
  for (int i = 0; i < 13; i++)
    if (in_sizes[i] != exp_sz[i]) {
      sentinel_k<<<5, 64, 0, stream>>>(outp, 1000.f + 100.f*i); return;
    }
  if (ws_size < (37u << 20)) { sentinel_k<<<5, 64, 0, stream>>>(outp, 500.f); return; }

  char* wsb = (char*)d_ws;
  const float* x    = (const float*)d_in[0];
  const float* Wc1  = (const float*)d_in[1];
  const float* Dc1  = (const float*)d_in[2];
  const float* Wc2  = (const float*)d_in[3];
  const float* Dc2  = (const float*)d_in[4];
  const float* Wc3  = (const float*)d_in[5];
  const float* Dc3  = (const float*)d_in[6];
  const float* Wc4  = (const float*)d_in[7];
  const float* Dc4  = (const float*)d_in[8];
  const float* Wd1  = (const float*)d_in[9];
  const float* Dd1  = (const float*)d_in[10];
  const float* Wout = (const float*)d_in[11];
  const float* Dout = (const float*)d_in[12];

  // ws layout (lifetime-safe):
  //   [1.0,1.8 MiB): Wt2/Wt3/Wt4 | A=[2,19 MiB) B=[19,36 MiB)
  unsigned short* Wt2 = (unsigned short*)(wsb + (1u << 20));
  unsigned short* Wt3 = (unsigned short*)(wsb + (1u << 20) + 262144);
  unsigned short* Wt4 = (unsigned short*)(wsb + (1u << 20) + 524288);
  unsigned short* U1 = (unsigned short*)(wsb + (2u  << 20)); // 16.78 MB
  unsigned short* P2 = (unsigned short*)(wsb + (19u << 20)); // 4.2 MB (conv2+pool out)
  unsigned short* U3 = (unsigned short*)(wsb + (2u  << 20)); // 8.4 MB (U1 dead)
  unsigned short* P4 = (unsigned short*)(wsb + (19u << 20)); // 2.1 MB (P2 dead)
  float* part        = (float*)(wsb + (2u  << 20));          // 8.4 MB (U3 dead)

  wtrans_all<<<dim3(72, 3), 256, 0, stream>>>(Wc2, Wc3, Wc4, Wt2, Wt3, Wt4);
  conv1_k<<<dim3(64, 32), 256, 0, stream>>>(x, Wc1, Dc1, U1);
  conv_mfma<64, 64, 64, true><<<dim3(32, 32), 256, 0, stream>>>(U1, Wt2, Dc2, P2);
  conv_mfma<64, 128, 32, false><<<dim3(32, 32), 256, 0, stream>>>(P2, Wt3, Dc3, U3);
  conv_mfma<128, 128, 32, true><<<dim3(16, 32), 256, 0, stream>>>(U3, Wt4, Dc4, P4);
  dense_k<<<512, 256, 0, stream>>>(P4, Wd1, part);
  tail_k<<<32, 256, 0, stream>>>(part, Dd1, Wout, Dout, outp);
}